// Round 2
// baseline (111.226 us; speedup 1.0000x reference)
//
#include <hip/hip_runtime.h>
#include <math.h>

// Problem constants (from reference)
#define BATCH    32
#define LSEQ     512
#define DDIM     1024
#define SSIZE    256          // K dimension
#define LATENT   256          // output cols
#define COEF     0.1f

#define ROWS     4096         // B * NTOK * NSEC
#define COLS     256
#define KDIM     256

// Main-kernel tiling: 32 rows x 64 cols per block, 256 threads,
// 2x4 micro-tile per thread. Grid = 128 x 4 = 512 blocks = 2 blocks/CU
// -> 8 waves/CU (2/SIMD) for latency hiding.
#define TR   32
#define TC   64
#define STR  260   // LDS row stride (floats): (4r + k) mod 32 spreads 8 wave-rows
                   // across 8 distinct bank groups -> conflict-free b128 reads

// Semantics collapse (verified R1, absmax 3.9e-3): M = inverse(C) exactly and
// the band mask is constant along the transformed axis, so the whole spectral
// chain reduces to  out[row,o] = tanh( scale(row) * dot(enc_row, W[o,:]) + b[o] )
// with scale applied in the epilogue (algebraically identical).

__device__ __forceinline__ float tanh_fast(float x) {
    // 1 - 2/(e^{2x}+1): exact limits at +/-inf, ~1e-6 abs err via v_exp_f32
    return 1.0f - 2.0f / (__expf(2.0f * x) + 1.0f);
}

__global__ __launch_bounds__(256, 8)
void transpose_w_kernel(const float* __restrict__ W, float* __restrict__ Wt) {
    __shared__ float tile[32][33];
    const int tx = threadIdx.x;        // 0..31
    const int ty = threadIdx.y;        // 0..7
    const int bx = blockIdx.x;         // k-block, 0..7
    const int by = blockIdx.y;         // o-block, 0..7
    #pragma unroll
    for (int i = 0; i < 4; ++i) {
        const int o = by * 32 + ty + i * 8;
        const int k = bx * 32 + tx;
        tile[ty + i * 8][tx] = W[o * KDIM + k];
    }
    __syncthreads();
    #pragma unroll
    for (int i = 0; i < 4; ++i) {
        const int k = bx * 32 + ty + i * 8;
        const int o = by * 32 + tx;
        Wt[k * COLS + o] = tile[tx][ty + i * 8];
    }
}

__global__ __launch_bounds__(256, 2)
void spectral_gemm_kernel(const float* __restrict__ enc,
                          const float* __restrict__ Wt,   // [k][o]
                          const float* __restrict__ bias,
                          float* __restrict__ out) {
    __shared__ float As[TR * STR];     // 33280 B

    const int t      = threadIdx.x;
    const int tile_r = blockIdx.x * TR;   // 128 row-tiles
    const int tile_c = blockIdx.y * TC;   // 4 col-tiles

    // ---- stage A: rows tile_r..tile_r+31 are one contiguous 32KB span of enc
    // (rows within a batch segment; tile_r%128 in {0,32,64,96}) ----
    const float* src = enc + (long)(tile_r >> 7) * (long)(LSEQ * DDIM)
                           + (long)(tile_r & 127) * 256;
    #pragma unroll
    for (int it = 0; it < 8; ++it) {
        const int f = t + it * 256;        // float4 index in [0, 2048)
        const int r = f >> 6;              // local row
        const int k = (f & 63) << 2;       // k offset
        const float4 v = *(const float4*)(src + (long)f * 4);
        *(float4*)&As[r * STR + k] = v;
    }
    __syncthreads();

    const int ty = t >> 4;                 // 0..15 -> rows 2ty, 2ty+1
    const int tx = t & 15;                 // cols tile_c + tx*4 .. +3
    const int r0 = 2 * ty;
    const float* wp = Wt + tile_c + tx * 4;

    float acc0x = 0.f, acc0y = 0.f, acc0z = 0.f, acc0w = 0.f;
    float acc1x = 0.f, acc1y = 0.f, acc1z = 0.f, acc1w = 0.f;

    #pragma unroll 4
    for (int k = 0; k < KDIM; k += 4) {
        const float4 a0 = *(const float4*)&As[r0 * STR + k];
        const float4 a1 = *(const float4*)&As[(r0 + 1) * STR + k];
        const float4 w0 = *(const float4*)(wp + (long)(k + 0) * COLS);
        const float4 w1 = *(const float4*)(wp + (long)(k + 1) * COLS);
        const float4 w2 = *(const float4*)(wp + (long)(k + 2) * COLS);
        const float4 w3 = *(const float4*)(wp + (long)(k + 3) * COLS);

        acc0x += a0.x * w0.x; acc0y += a0.x * w0.y; acc0z += a0.x * w0.z; acc0w += a0.x * w0.w;
        acc0x += a0.y * w1.x; acc0y += a0.y * w1.y; acc0z += a0.y * w1.z; acc0w += a0.y * w1.w;
        acc0x += a0.z * w2.x; acc0y += a0.z * w2.y; acc0z += a0.z * w2.z; acc0w += a0.z * w2.w;
        acc0x += a0.w * w3.x; acc0y += a0.w * w3.y; acc0z += a0.w * w3.z; acc0w += a0.w * w3.w;

        acc1x += a1.x * w0.x; acc1y += a1.x * w0.y; acc1z += a1.x * w0.z; acc1w += a1.x * w0.w;
        acc1x += a1.y * w1.x; acc1y += a1.y * w1.y; acc1z += a1.y * w1.z; acc1w += a1.y * w1.w;
        acc1x += a1.z * w2.x; acc1y += a1.z * w2.y; acc1z += a1.z * w2.z; acc1w += a1.z * w2.w;
        acc1x += a1.w * w3.x; acc1y += a1.w * w3.y; acc1z += a1.w * w3.z; acc1w += a1.w * w3.w;
    }

    // ---- epilogue: per-row scale, bias, tanh ----
    const float4 b4 = *(const float4*)&bias[tile_c + tx * 4];
    float accs[2][4] = {{acc0x, acc0y, acc0z, acc0w}, {acc1x, acc1y, acc1z, acc1w}};
    #pragma unroll
    for (int i = 0; i < 2; ++i) {
        const int row = tile_r + r0 + i;
        const int n = row & 3;
        const int l = (row >> 2) & 31;
        const float scale = (n == 0 || (n == 1 && l >= 16)) ? 1.0f : COEF;
        float4 o;
        o.x = tanh_fast(scale * accs[i][0] + b4.x);
        o.y = tanh_fast(scale * accs[i][1] + b4.y);
        o.z = tanh_fast(scale * accs[i][2] + b4.z);
        o.w = tanh_fast(scale * accs[i][3] + b4.w);
        *(float4*)&out[(long)row * COLS + tile_c + tx * 4] = o;
    }
}

extern "C" void kernel_launch(void* const* d_in, const int* in_sizes, int n_in,
                              void* d_out, int out_size, void* d_ws, size_t ws_size,
                              hipStream_t stream) {
    const float* enc  = (const float*)d_in[0];   // [32, 512, 1024]
    const float* W    = (const float*)d_in[1];   // [256, 256]
    const float* bias = (const float*)d_in[2];   // [256]
    float* out = (float*)d_out;                  // [32, 32, 4, 256]
    float* Wt  = (float*)d_ws;                   // [256, 256] transposed W

    transpose_w_kernel<<<dim3(8, 8), dim3(32, 8), 0, stream>>>(W, Wt);

    dim3 grid(ROWS / TR, COLS / TC);             // 128 x 4 = 512 blocks
    spectral_gemm_kernel<<<grid, dim3(256), 0, stream>>>(enc, Wt, bias, out);
}

// Round 3
// 102.862 us; speedup vs baseline: 1.0813x; 1.0813x over previous
//
#include <hip/hip_runtime.h>
#include <math.h>

// Problem constants
#define LSEQ   512
#define DDIM   1024
#define KDIM   256       // SSIZE
#define COLS   256       // LATENT
#define ROWS   4096      // B * NTOK * NSEC
#define COEF   0.1f

// Tiling: 32 rows x 64 cols per block, 256 threads, 2x4 micro-tile.
// Grid 128x4 = 512 blocks = 2/CU = 8 waves/CU (2/SIMD).
#define TR    32
#define TC    64
#define BK    64
#define STRA  260   // As[r][k] stride: bank-start 4r%32 distinct for the 8 rows/wave
#define STRW  68    // Ws[o][k] stride: with col=tx+16c, lanes hit consecutive o ->
                    // bank-start 4o%32, 2-way aliasing = free (m136)

// Semantics collapse (verified R1/R2, absmax 3.9e-3): M = inverse(C) and the
// band mask is constant along the transformed (batch) axis, so the spectral
// chain reduces to  out[row,o] = tanh( scale(row)*dot(enc_row, W[o,:]) + b[o] ).

__device__ __forceinline__ float tanh_fast(float x) {
    // 1 - 2/(e^{2x}+1): exact +/-inf limits, ~1e-6 abs err via v_exp_f32
    return 1.0f - 2.0f / (__expf(2.0f * x) + 1.0f);
}

__global__ __launch_bounds__(256, 2)
void spectral_gemm_kernel(const float* __restrict__ enc,
                          const float* __restrict__ W,
                          const float* __restrict__ bias,
                          float* __restrict__ out) {
    __shared__ float As[TR * STRA];   // 33280 B — full-K A tile, staged once
    __shared__ float Ws[TC * STRW];   // 17408 B — one BK-phase of W
    // 50688 B total -> 2 blocks/CU resident (grid-limited), 8 waves/CU

    const int t      = threadIdx.x;
    const int tile_r = blockIdx.x * TR;
    const int tile_c = blockIdx.y * TC;

    // ---- stage A for full K: rows tile_r..+31 are one contiguous 32 KB span ----
    const float* srcA = enc + (size_t)(tile_r >> 7) * (size_t)(LSEQ * DDIM)
                            + (size_t)(tile_r & 127) * KDIM;
    #pragma unroll
    for (int it = 0; it < 8; ++it) {
        const int f  = t + it * 256;      // float4 index, 0..2047
        const int r  = f >> 6;            // local row
        const int k4 = f & 63;            // float4 within row
        const float4 v = *(const float4*)(srcA + (size_t)f * 4);
        *(float4*)&As[r * STRA + k4 * 4] = v;   // bank-even b128 writes
    }

    const int tx = t & 15;                // 16 col groups (strided cols tx+16c)
    const int ty = t >> 4;                // 16 row groups -> rows 2ty, 2ty+1
    const int r0 = 2 * ty;

    float acc[2][4] = {{0.f,0.f,0.f,0.f},{0.f,0.f,0.f,0.f}};

    for (int p = 0; p < 4; ++p) {
        const int kk = p * BK;

        // ---- stage W phase: 64 rows x 16 float4, coalesced 256B/16-lane ----
        #pragma unroll
        for (int it = 0; it < 4; ++it) {
            const int o  = (t >> 4) + it * 16;
            const int k4 = t & 15;
            const float4 v =
                *(const float4*)&W[(size_t)(tile_c + o) * KDIM + kk + k4 * 4];
            *(float4*)&Ws[o * STRW + k4 * 4] = v;
        }
        __syncthreads();

        // ---- inner: per 4k, 6 ds_read_b128 + 32 FMA (FMA-issue-bound) ----
        #pragma unroll 8
        for (int k = 0; k < BK; k += 4) {
            const float4 a0 = *(const float4*)&As[r0 * STRA + kk + k];
            const float4 a1 = *(const float4*)&As[(r0 + 1) * STRA + kk + k];
            float4 w[4];
            #pragma unroll
            for (int c = 0; c < 4; ++c)
                w[c] = *(const float4*)&Ws[(tx + 16 * c) * STRW + k];
            #pragma unroll
            for (int c = 0; c < 4; ++c) {
                acc[0][c] += a0.x * w[c].x;
                acc[0][c] += a0.y * w[c].y;
                acc[0][c] += a0.z * w[c].z;
                acc[0][c] += a0.w * w[c].w;
                acc[1][c] += a1.x * w[c].x;
                acc[1][c] += a1.y * w[c].y;
                acc[1][c] += a1.z * w[c].z;
                acc[1][c] += a1.w * w[c].w;
            }
        }
        __syncthreads();   // protect Ws before next phase overwrites it
    }

    // ---- epilogue: per-row scale, bias, tanh; strided cols, coalesced lanes ----
    #pragma unroll
    for (int i = 0; i < 2; ++i) {
        const int row = tile_r + r0 + i;
        const int n = row & 3;
        const int l = (row >> 2) & 31;
        const float scale = (n == 0 || (n == 1 && l >= 16)) ? 1.0f : COEF;
        #pragma unroll
        for (int c = 0; c < 4; ++c) {
            const int col = tile_c + tx + 16 * c;
            out[(size_t)row * COLS + col] = tanh_fast(scale * acc[i][c] + bias[col]);
        }
    }
}

extern "C" void kernel_launch(void* const* d_in, const int* in_sizes, int n_in,
                              void* d_out, int out_size, void* d_ws, size_t ws_size,
                              hipStream_t stream) {
    const float* enc  = (const float*)d_in[0];   // [32, 512, 1024]
    const float* W    = (const float*)d_in[1];   // [256, 256]
    const float* bias = (const float*)d_in[2];   // [256]
    float* out = (float*)d_out;                  // [32, 32, 4, 256]

    dim3 grid(ROWS / TR, COLS / TC);             // 128 x 4 = 512 blocks
    spectral_gemm_kernel<<<grid, dim3(256), 0, stream>>>(enc, W, bias, out);
}